// Round 4
// baseline (686.927 us; speedup 1.0000x reference)
//
#include <hip/hip_runtime.h>
#include <stdint.h>

typedef __bf16 bf16_t;
typedef bf16_t bf16x8 __attribute__((ext_vector_type(8)));
typedef float f32x4 __attribute__((ext_vector_type(4)));

#define DIM 256
#define NNODES 50000

// ---------------- edge dtype detection (int64 vs int32) ----------------
// flags[0] = 1 if edge_index is int64. For int64 (values < 2^31), odd int32
// words are high halves == 0; for int32, odd words are random node ids.
__global__ void detect_kernel(const int* __restrict__ ei, int* __restrict__ flags) {
    __shared__ int s_zero;
    if (threadIdx.x == 0) s_zero = 0;
    __syncthreads();
    int z = (ei[2 * threadIdx.x + 1] == 0) ? 1 : 0;   // words [1..511], in-bounds either way
    atomicAdd(&s_zero, z);
    __syncthreads();
    if (threadIdx.x == 0) flags[0] = (s_zero > 128) ? 1 : 0;
}

__device__ __forceinline__ int load_edge(const int* __restrict__ ei, int E, int f64,
                                         int which /*0=src,1=dst*/, int e) {
    int v = f64 ? ei[(size_t)which * 2 * E + 2 * (size_t)e]   // int64 low word (LE)
                : ei[(size_t)which * E + (size_t)e];
    return min(max(v, 0), NNODES - 1);                        // defensive clamp
}

// ---------------- CSR build ----------------

__global__ void zero_counts_kernel(int* __restrict__ counts, int n) {
    int i = blockIdx.x * blockDim.x + threadIdx.x;
    if (i < n) counts[i] = 0;
}

__global__ void hist_kernel(const int* __restrict__ ei, int E, const int* __restrict__ flags,
                            int* __restrict__ counts) {
    int e = blockIdx.x * blockDim.x + threadIdx.x;
    if (e < E) atomicAdd(&counts[load_edge(ei, E, flags[0], 1, e)], 1);
}

__global__ __launch_bounds__(1024) void scan_kernel(const int* __restrict__ counts,
                                                    int* __restrict__ offsets, int n) {
    __shared__ int sm[1024];
    __shared__ int s_carry;
    int tid = threadIdx.x;
    if (tid == 0) { s_carry = 0; offsets[0] = 0; }
    __syncthreads();
    for (int base = 0; base < n; base += 1024) {
        int idx = base + tid;
        int v = (idx < n) ? counts[idx] : 0;
        sm[tid] = v;
        __syncthreads();
        #pragma unroll
        for (int off = 1; off < 1024; off <<= 1) {
            int t = (tid >= off) ? sm[tid - off] : 0;
            __syncthreads();
            sm[tid] += t;
            __syncthreads();
        }
        int c = s_carry;
        if (idx < n) offsets[idx + 1] = c + sm[tid];
        __syncthreads();
        if (tid == 0) s_carry = c + sm[1023];
        __syncthreads();
    }
}

__global__ void dinv_cursor_kernel(const int* __restrict__ counts, const int* __restrict__ offsets,
                                   float* __restrict__ dinv, int* __restrict__ cursor, int n) {
    int i = blockIdx.x * blockDim.x + threadIdx.x;
    if (i < n) {
        dinv[i] = rsqrtf((float)(counts[i] + 1));  // +1 self-loop; deg > 0 always
        cursor[i] = offsets[i];
    }
}

__global__ void scatter_kernel(const int* __restrict__ ei, int E, const int* __restrict__ flags,
                               int* __restrict__ cursor, int* __restrict__ csr_src) {
    int e = blockIdx.x * blockDim.x + threadIdx.x;
    if (e < E) {
        int s = load_edge(ei, E, flags[0], 0, e);
        int d = load_edge(ei, E, flags[0], 1, e);
        int pos = atomicAdd(&cursor[d], 1);
        if (pos >= 0 && pos < E) csr_src[pos] = s;
    }
}

// ---------------- weight prep: fp32 W[k][n] -> bf16 split-transposed Wt_hi/lo[n][k] ----------------

__global__ void convertT_w_kernel(const float* __restrict__ W,
                                  bf16_t* __restrict__ Wt_hi, bf16_t* __restrict__ Wt_lo) {
    int nn = blockIdx.x, k = threadIdx.x;
    float v = W[k * DIM + nn];
    bf16_t hi = (bf16_t)v;
    Wt_hi[nn * DIM + k] = hi;
    Wt_lo[nn * DIM + k] = (bf16_t)(v - (float)hi);
}

// ---------------- GEMM: H[M,256] = X[M,256] @ W, fp32 in/out, split-bf16 MFMA ----------------

__global__ __launch_bounds__(256) void gemm_kernel(const float* __restrict__ X,
                                                   const bf16_t* __restrict__ Wt_hi,
                                                   const bf16_t* __restrict__ Wt_lo,
                                                   float* __restrict__ H, int M) {
    int wave = threadIdx.x >> 6;
    int lane = threadIdx.x & 63;
    int tiles = M >> 4;                    // 50000/16 = 3125 exactly
    int tile = blockIdx.x * 4 + wave;
    if (tile >= tiles) return;             // wave-uniform exit
    int row0 = tile << 4;
    int m = lane & 15;
    int quad = lane >> 4;

    const float* xrow = X + (size_t)(row0 + m) * DIM;
    f32x4 acc[16] = {};

    for (int k0 = 0; k0 < DIM; k0 += 32) {
        // A fragment (verified m120): A[m=lane&15][k=quad*8+j]; split fp32 -> hi+lo bf16
        bf16x8 ahi, alo;
        #pragma unroll
        for (int j = 0; j < 8; j++) {
            float v = xrow[k0 + quad * 8 + j];
            bf16_t h = (bf16_t)v;
            ahi[j] = h;
            alo[j] = (bf16_t)(v - (float)h);
        }
        #pragma unroll
        for (int nt = 0; nt < 16; nt++) {
            // B fragment: n = nt*16 + (lane&15), k = k0 + quad*8 + j -> contiguous 16B
            size_t wo = (size_t)(nt * 16 + m) * DIM + k0 + quad * 8;
            bf16x8 bhi = *(const bf16x8*)(Wt_hi + wo);
            bf16x8 blo = *(const bf16x8*)(Wt_lo + wo);
            acc[nt] = __builtin_amdgcn_mfma_f32_16x16x32_bf16(alo, bhi, acc[nt], 0, 0, 0);
            acc[nt] = __builtin_amdgcn_mfma_f32_16x16x32_bf16(ahi, blo, acc[nt], 0, 0, 0);
            acc[nt] = __builtin_amdgcn_mfma_f32_16x16x32_bf16(ahi, bhi, acc[nt], 0, 0, 0);
        }
    }

    // C/D layout (verified m89): col = lane&15 (n), row = quad*4 + reg (m)
    #pragma unroll
    for (int nt = 0; nt < 16; nt++) {
        #pragma unroll
        for (int r = 0; r < 4; r++) {
            H[(size_t)(row0 + quad * 4 + r) * DIM + nt * 16 + m] = acc[nt][r];
        }
    }
}

// ---------------- Aggregation: out = relu(D^-1/2 (A+I) D^-1/2 H + b), fp32 ----------------

__global__ __launch_bounds__(256) void aggregate_kernel(const float* __restrict__ H,
                                                        const float* __restrict__ dinv,
                                                        const int* __restrict__ offsets,
                                                        const int* __restrict__ csr_src,
                                                        const float* __restrict__ bias,
                                                        float* __restrict__ out, int n) {
    int i = blockIdx.x;
    int f = threadIdx.x;
    float dii = dinv[i];
    float acc = H[(size_t)i * DIM + f] * dii * dii;  // self-loop
    int e0 = offsets[i], e1 = offsets[i + 1];
    for (int e = e0; e < e1; ++e) {
        int s = csr_src[e];
        acc += H[(size_t)s * DIM + f] * (dinv[s] * dii);
    }
    out[(size_t)i * DIM + f] = fmaxf(acc + bias[f], 0.0f);
}

// ---------------- launch ----------------

extern "C" void kernel_launch(void* const* d_in, const int* in_sizes, int n_in,
                              void* d_out, int out_size, void* d_ws, size_t ws_size,
                              hipStream_t stream) {
    const float* x  = (const float*)d_in[0];
    const int*   ei = (const int*)d_in[1];
    const float* W1 = (const float*)d_in[2];
    const float* b1 = (const float*)d_in[3];
    const float* W2 = (const float*)d_in[4];
    const float* b2 = (const float*)d_in[5];
    float* out = (float*)d_out;

    const int n = NNODES;
    const int E = in_sizes[1] / 2;

    // workspace carve-up (256B-aligned); total ~54.2 MB (same footprint as prior rounds)
    char* ws = (char*)d_ws;
    size_t off = 0;
    auto alloc = [&](size_t bytes) -> char* {
        char* p = ws + off;
        off += (bytes + 255) & ~(size_t)255;
        return p;
    };
    int*    flags   = (int*)alloc(256);
    float*  dinv    = (float*)alloc((size_t)n * 4);
    int*    counts  = (int*)alloc((size_t)n * 4);
    int*    offsets = (int*)alloc((size_t)(n + 1) * 4);
    int*    cursor  = (int*)alloc((size_t)n * 4);
    int*    csr_src = (int*)alloc((size_t)E * 4);
    bf16_t* Wt1h    = (bf16_t*)alloc((size_t)DIM * DIM * 2);
    bf16_t* Wt1l    = (bf16_t*)alloc((size_t)DIM * DIM * 2);
    bf16_t* Wt2h    = (bf16_t*)alloc((size_t)DIM * DIM * 2);
    bf16_t* Wt2l    = (bf16_t*)alloc((size_t)DIM * DIM * 2);
    float*  P       = (float*)alloc((size_t)n * DIM * 4);    // fp32 GEMM output buffer

    // edge dtype + CSR build (shared by both layers)
    detect_kernel<<<1, 256, 0, stream>>>(ei, flags);
    zero_counts_kernel<<<(n + 255) / 256, 256, 0, stream>>>(counts, n);
    hist_kernel<<<(E + 255) / 256, 256, 0, stream>>>(ei, E, flags, counts);
    scan_kernel<<<1, 1024, 0, stream>>>(counts, offsets, n);
    dinv_cursor_kernel<<<(n + 255) / 256, 256, 0, stream>>>(counts, offsets, dinv, cursor, n);
    scatter_kernel<<<(E + 255) / 256, 256, 0, stream>>>(ei, E, flags, cursor, csr_src);

    convertT_w_kernel<<<DIM, DIM, 0, stream>>>(W1, Wt1h, Wt1l);
    convertT_w_kernel<<<DIM, DIM, 0, stream>>>(W2, Wt2h, Wt2l);

    int gemm_blocks = ((n >> 4) + 3) / 4;  // 3125 wave-tiles / 4 waves per block

    // Layer 1: gemm(x) -> P, aggregate(P) -> d_out (scratch use of output buffer)
    gemm_kernel<<<gemm_blocks, 256, 0, stream>>>(x, Wt1h, Wt1l, P, n);
    aggregate_kernel<<<n, 256, 0, stream>>>(P, dinv, offsets, csr_src, b1, out, n);
    // Layer 2: gemm(d_out) -> P, aggregate(P) -> d_out (final)
    gemm_kernel<<<gemm_blocks, 256, 0, stream>>>(out, Wt2h, Wt2l, P, n);
    aggregate_kernel<<<n, 256, 0, stream>>>(P, dinv, offsets, csr_src, b2, out, n);
}

// Round 5
// 399.965 us; speedup vs baseline: 1.7175x; 1.7175x over previous
//
#include <hip/hip_runtime.h>
#include <stdint.h>

typedef __bf16 bf16_t;
typedef bf16_t bf16x8 __attribute__((ext_vector_type(8)));
typedef float f32x4 __attribute__((ext_vector_type(4)));

#define DIM 256
#define NNODES 50000

// ---------------- edge dtype detection (int64 vs int32) ----------------
__global__ void detect_kernel(const int* __restrict__ ei, int* __restrict__ flags) {
    __shared__ int s_zero;
    if (threadIdx.x == 0) s_zero = 0;
    __syncthreads();
    int z = (ei[2 * threadIdx.x + 1] == 0) ? 1 : 0;   // odd words: int64 high halves == 0
    atomicAdd(&s_zero, z);
    __syncthreads();
    if (threadIdx.x == 0) flags[0] = (s_zero > 128) ? 1 : 0;
}

__device__ __forceinline__ int load_edge(const int* __restrict__ ei, int E, int f64,
                                         int which /*0=src,1=dst*/, int e) {
    int v = f64 ? ei[(size_t)which * 2 * E + 2 * (size_t)e]   // int64 low word (LE)
                : ei[(size_t)which * E + (size_t)e];
    return min(max(v, 0), NNODES - 1);
}

// ---------------- CSR build ----------------

__global__ void zero_counts_kernel(int* __restrict__ counts, int n) {
    int i = blockIdx.x * blockDim.x + threadIdx.x;
    if (i < n) counts[i] = 0;
}

__global__ void hist_kernel(const int* __restrict__ ei, int E, const int* __restrict__ flags,
                            int* __restrict__ counts) {
    int e = blockIdx.x * blockDim.x + threadIdx.x;
    if (e < E) atomicAdd(&counts[load_edge(ei, E, flags[0], 1, e)], 1);
}

// hierarchical scan: A) per-block inclusive scan, B) scan of block sums, C) fixup + dinv/cursor
__global__ __launch_bounds__(256) void scanA_kernel(const int* __restrict__ counts,
                                                    int* __restrict__ offsets,
                                                    int* __restrict__ bsums, int n) {
    __shared__ int sm[256];
    int b = blockIdx.x, t = threadIdx.x;
    int idx = b * 256 + t;
    int v = (idx < n) ? counts[idx] : 0;
    sm[t] = v;
    __syncthreads();
    #pragma unroll
    for (int off = 1; off < 256; off <<= 1) {
        int u = (t >= off) ? sm[t - off] : 0;
        __syncthreads();
        sm[t] += u;
        __syncthreads();
    }
    if (idx < n) offsets[idx + 1] = sm[t];   // inclusive within block (no base yet)
    if (t == 255) bsums[b] = sm[255];
}

__global__ __launch_bounds__(256) void scanB_kernel(int* __restrict__ bsums, int nb) {
    __shared__ int sm[256];
    int t = threadIdx.x;
    int v = (t < nb) ? bsums[t] : 0;
    sm[t] = v;
    __syncthreads();
    #pragma unroll
    for (int off = 1; off < 256; off <<= 1) {
        int u = (t >= off) ? sm[t - off] : 0;
        __syncthreads();
        sm[t] += u;
        __syncthreads();
    }
    if (t < nb) bsums[t] = sm[t] - v;        // exclusive block base
}

__global__ __launch_bounds__(256) void scanC_kernel(const int* __restrict__ counts,
                                                    const int* __restrict__ bsums,
                                                    int* __restrict__ offsets,
                                                    float* __restrict__ dinv,
                                                    int* __restrict__ cursor, int n) {
    int b = blockIdx.x;
    int idx = b * 256 + threadIdx.x;
    if (idx == 0) offsets[0] = 0;
    if (idx < n) {
        int incl = offsets[idx + 1] + bsums[b];
        offsets[idx + 1] = incl;
        cursor[idx] = incl - counts[idx];     // exclusive offset
        dinv[idx] = rsqrtf((float)(counts[idx] + 1));  // +1 self-loop
    }
}

__global__ void scatter_kernel(const int* __restrict__ ei, int E, const int* __restrict__ flags,
                               const float* __restrict__ dinv, int* __restrict__ cursor,
                               int* __restrict__ csr_src, float* __restrict__ csr_norm) {
    int e = blockIdx.x * blockDim.x + threadIdx.x;
    if (e < E) {
        int s = load_edge(ei, E, flags[0], 0, e);
        int d = load_edge(ei, E, flags[0], 1, e);
        int pos = atomicAdd(&cursor[d], 1);
        if (pos >= 0 && pos < E) {
            csr_src[pos] = s;
            csr_norm[pos] = dinv[s] * dinv[d];  // precomputed edge weight
        }
    }
}

// ---------------- weight prep: fp32 W[k][n] -> bf16 split-transposed Wt_hi/lo[n][k] ----------------

__global__ void convertT_w_kernel(const float* __restrict__ W,
                                  bf16_t* __restrict__ Wt_hi, bf16_t* __restrict__ Wt_lo) {
    int nn = blockIdx.x, k = threadIdx.x;
    float v = W[k * DIM + nn];
    bf16_t hi = (bf16_t)v;
    Wt_hi[nn * DIM + k] = hi;
    Wt_lo[nn * DIM + k] = (bf16_t)(v - (float)hi);
}

// ---------------- GEMM: H[M,256] = X[M,256] @ W, LDS-staged B, 2 row-tiles/wave ----------------
// Block = 4 waves, covers 8 tiles (128 rows). B slice [256n x 32k] hi+lo staged in LDS
// with rows padded to 40 shorts (80 B) -> 2-way-max bank aliasing (free, m136).

__global__ __launch_bounds__(256) void gemm_kernel(const float* __restrict__ X,
                                                   const bf16_t* __restrict__ Wth,
                                                   const bf16_t* __restrict__ Wtl,
                                                   float* __restrict__ H, int M) {
    __shared__ bf16_t sBh[256 * 40];
    __shared__ bf16_t sBl[256 * 40];
    int tid  = threadIdx.x;
    int wave = tid >> 6, lane = tid & 63;
    int m = lane & 15, quad = lane >> 4;
    int t0 = blockIdx.x * 8 + wave * 2;          // this wave's two row-tiles

    f32x4 acc[2][16] = {};

    for (int k0 = 0; k0 < DIM; k0 += 32) {
        // stage: thread t copies W row n=t, cols [k0,k0+32) (64 B hi + 64 B lo)
        {
            const bf16x8* gh = (const bf16x8*)(Wth + (size_t)tid * DIM + k0);
            const bf16x8* gl = (const bf16x8*)(Wtl + (size_t)tid * DIM + k0);
            bf16x8* dh = (bf16x8*)(sBh + tid * 40);
            bf16x8* dl = (bf16x8*)(sBl + tid * 40);
            #pragma unroll
            for (int j = 0; j < 4; j++) { dh[j] = gh[j]; dl[j] = gl[j]; }
        }
        __syncthreads();

        // A fragments for both tiles: A[m=lane&15][k=quad*8+j], split fp32 -> hi+lo
        bf16x8 ah[2], al[2];
        #pragma unroll
        for (int r = 0; r < 2; r++) {
            int row = (t0 + r) * 16 + m;
            row = min(row, M - 1);               // clamp for tail tiles (stores predicated)
            const f32x4* xp = (const f32x4*)(X + (size_t)row * DIM + k0 + quad * 8);
            f32x4 x0 = xp[0], x1 = xp[1];
            #pragma unroll
            for (int j = 0; j < 4; j++) {
                bf16_t h0 = (bf16_t)x0[j];
                ah[r][j] = h0; al[r][j] = (bf16_t)(x0[j] - (float)h0);
                bf16_t h1 = (bf16_t)x1[j];
                ah[r][j + 4] = h1; al[r][j + 4] = (bf16_t)(x1[j] - (float)h1);
            }
        }

        #pragma unroll
        for (int nt = 0; nt < 16; nt++) {
            // B fragment: n = nt*16+m, k = quad*8+j -> 16 B at padded row
            const bf16x8 bh = *(const bf16x8*)(sBh + (nt * 16 + m) * 40 + quad * 8);
            const bf16x8 bl = *(const bf16x8*)(sBl + (nt * 16 + m) * 40 + quad * 8);
            #pragma unroll
            for (int r = 0; r < 2; r++) {
                acc[r][nt] = __builtin_amdgcn_mfma_f32_16x16x32_bf16(al[r], bh, acc[r][nt], 0, 0, 0);
                acc[r][nt] = __builtin_amdgcn_mfma_f32_16x16x32_bf16(ah[r], bl, acc[r][nt], 0, 0, 0);
                acc[r][nt] = __builtin_amdgcn_mfma_f32_16x16x32_bf16(ah[r], bh, acc[r][nt], 0, 0, 0);
            }
        }
        __syncthreads();
    }

    // C/D layout (verified): out row = quad*4+reg, out col = nt*16 + (lane&15)
    #pragma unroll
    for (int r = 0; r < 2; r++) {
        int rowb = (t0 + r) * 16 + quad * 4;
        #pragma unroll
        for (int nt = 0; nt < 16; nt++) {
            #pragma unroll
            for (int rr = 0; rr < 4; rr++) {
                int row = rowb + rr;
                if (row < M) H[(size_t)row * DIM + nt * 16 + m] = acc[r][nt][rr];
            }
        }
    }
}

// ---------------- Aggregation: 4 nodes/block, 64 lanes x float4, 4-edge unroll ----------------

__global__ __launch_bounds__(256) void aggregate_kernel(const float* __restrict__ H,
                                                        const int* __restrict__ offsets,
                                                        const int* __restrict__ csr_src,
                                                        const float* __restrict__ csr_norm,
                                                        const float* __restrict__ dinv,
                                                        const float* __restrict__ bias,
                                                        float* __restrict__ out, int n) {
    int g = threadIdx.x >> 6;
    int l = threadIdx.x & 63;
    int i = blockIdx.x * 4 + g;
    if (i >= n) return;                       // n % 4 == 0, never taken; wave-uniform anyway
    float dii = dinv[i];
    f32x4 acc = *(const f32x4*)(H + (size_t)i * DIM + l * 4) * (dii * dii);  // self-loop
    int e0 = offsets[i], e1 = offsets[i + 1];
    int e = e0;
    for (; e + 4 <= e1; e += 4) {
        int s0 = csr_src[e], s1 = csr_src[e + 1], s2 = csr_src[e + 2], s3 = csr_src[e + 3];
        float w0 = csr_norm[e], w1 = csr_norm[e + 1], w2 = csr_norm[e + 2], w3 = csr_norm[e + 3];
        f32x4 h0 = *(const f32x4*)(H + (size_t)s0 * DIM + l * 4);
        f32x4 h1 = *(const f32x4*)(H + (size_t)s1 * DIM + l * 4);
        f32x4 h2 = *(const f32x4*)(H + (size_t)s2 * DIM + l * 4);
        f32x4 h3 = *(const f32x4*)(H + (size_t)s3 * DIM + l * 4);
        acc += h0 * w0 + h1 * w1 + h2 * w2 + h3 * w3;
    }
    for (; e < e1; e++) {
        acc += *(const f32x4*)(H + (size_t)csr_src[e] * DIM + l * 4) * csr_norm[e];
    }
    acc += *(const f32x4*)(bias + l * 4);
    f32x4 o;
    #pragma unroll
    for (int j = 0; j < 4; j++) o[j] = fmaxf(acc[j], 0.0f);
    *(f32x4*)(out + (size_t)i * DIM + l * 4) = o;
}

// ---------------- launch ----------------

extern "C" void kernel_launch(void* const* d_in, const int* in_sizes, int n_in,
                              void* d_out, int out_size, void* d_ws, size_t ws_size,
                              hipStream_t stream) {
    const float* x  = (const float*)d_in[0];
    const int*   ei = (const int*)d_in[1];
    const float* W1 = (const float*)d_in[2];
    const float* b1 = (const float*)d_in[3];
    const float* W2 = (const float*)d_in[4];
    const float* b2 = (const float*)d_in[5];
    float* out = (float*)d_out;

    const int n = NNODES;
    const int E = in_sizes[1] / 2;
    const int nb = (n + 255) / 256;   // 196 scan blocks

    char* ws = (char*)d_ws;
    size_t off = 0;
    auto alloc = [&](size_t bytes) -> char* {
        char* p = ws + off;
        off += (bytes + 255) & ~(size_t)255;
        return p;
    };
    int*    flags    = (int*)alloc(256);
    float*  dinv     = (float*)alloc((size_t)n * 4);
    int*    counts   = (int*)alloc((size_t)n * 4);
    int*    offsets  = (int*)alloc((size_t)(n + 1) * 4);
    int*    cursor   = (int*)alloc((size_t)n * 4);
    int*    bsums    = (int*)alloc((size_t)nb * 4);
    int*    csr_src  = (int*)alloc((size_t)E * 4);
    float*  csr_norm = (float*)alloc((size_t)E * 4);
    bf16_t* Wt1h     = (bf16_t*)alloc((size_t)DIM * DIM * 2);
    bf16_t* Wt1l     = (bf16_t*)alloc((size_t)DIM * DIM * 2);
    bf16_t* Wt2h     = (bf16_t*)alloc((size_t)DIM * DIM * 2);
    bf16_t* Wt2l     = (bf16_t*)alloc((size_t)DIM * DIM * 2);
    float*  P        = (float*)alloc((size_t)n * DIM * 4);

    detect_kernel<<<1, 256, 0, stream>>>(ei, flags);
    zero_counts_kernel<<<nb, 256, 0, stream>>>(counts, n);
    hist_kernel<<<(E + 255) / 256, 256, 0, stream>>>(ei, E, flags, counts);
    scanA_kernel<<<nb, 256, 0, stream>>>(counts, offsets, bsums, n);
    scanB_kernel<<<1, 256, 0, stream>>>(bsums, nb);
    scanC_kernel<<<nb, 256, 0, stream>>>(counts, bsums, offsets, dinv, cursor, n);
    scatter_kernel<<<(E + 255) / 256, 256, 0, stream>>>(ei, E, flags, dinv, cursor,
                                                        csr_src, csr_norm);

    convertT_w_kernel<<<DIM, DIM, 0, stream>>>(W1, Wt1h, Wt1l);
    convertT_w_kernel<<<DIM, DIM, 0, stream>>>(W2, Wt2h, Wt2l);

    int tiles = (n + 15) / 16;                 // 3125
    int gemm_blocks = (tiles + 7) / 8;         // 391
    int agg_blocks = n / 4;                    // 12500

    gemm_kernel<<<gemm_blocks, 256, 0, stream>>>(x, Wt1h, Wt1l, P, n);
    aggregate_kernel<<<agg_blocks, 256, 0, stream>>>(P, offsets, csr_src, csr_norm, dinv, b1, out, n);
    gemm_kernel<<<gemm_blocks, 256, 0, stream>>>(out, Wt2h, Wt2l, P, n);
    aggregate_kernel<<<agg_blocks, 256, 0, stream>>>(P, offsets, csr_src, csr_norm, dinv, b2, out, n);
}

// Round 6
// 336.220 us; speedup vs baseline: 2.0431x; 1.1896x over previous
//
#include <hip/hip_runtime.h>
#include <stdint.h>

typedef __bf16 bf16_t;
typedef bf16_t bf16x4 __attribute__((ext_vector_type(4)));
typedef bf16_t bf16x8 __attribute__((ext_vector_type(8)));
typedef float f32x4 __attribute__((ext_vector_type(4)));

#define DIM 256
#define NNODES 50000

// ---------------- edge dtype detection (int64 vs int32) ----------------
__global__ void detect_kernel(const int* __restrict__ ei, int* __restrict__ flags) {
    __shared__ int s_zero;
    if (threadIdx.x == 0) s_zero = 0;
    __syncthreads();
    int z = (ei[2 * threadIdx.x + 1] == 0) ? 1 : 0;   // odd words: int64 high halves == 0
    atomicAdd(&s_zero, z);
    __syncthreads();
    if (threadIdx.x == 0) flags[0] = (s_zero > 128) ? 1 : 0;
}

__device__ __forceinline__ int load_edge(const int* __restrict__ ei, int E, int f64,
                                         int which /*0=src,1=dst*/, int e) {
    int v = f64 ? ei[(size_t)which * 2 * E + 2 * (size_t)e]   // int64 low word (LE)
                : ei[(size_t)which * E + (size_t)e];
    return min(max(v, 0), NNODES - 1);
}

// ---------------- CSR build ----------------

__global__ void zero_counts_kernel(int* __restrict__ counts, int n) {
    int i = blockIdx.x * blockDim.x + threadIdx.x;
    if (i < n) counts[i] = 0;
}

__global__ void hist_kernel(const int* __restrict__ ei, int E, const int* __restrict__ flags,
                            int* __restrict__ counts) {
    int e = blockIdx.x * blockDim.x + threadIdx.x;
    if (e < E) atomicAdd(&counts[load_edge(ei, E, flags[0], 1, e)], 1);
}

__global__ __launch_bounds__(256) void scanA_kernel(const int* __restrict__ counts,
                                                    int* __restrict__ offsets,
                                                    int* __restrict__ bsums, int n) {
    __shared__ int sm[256];
    int b = blockIdx.x, t = threadIdx.x;
    int idx = b * 256 + t;
    int v = (idx < n) ? counts[idx] : 0;
    sm[t] = v;
    __syncthreads();
    #pragma unroll
    for (int off = 1; off < 256; off <<= 1) {
        int u = (t >= off) ? sm[t - off] : 0;
        __syncthreads();
        sm[t] += u;
        __syncthreads();
    }
    if (idx < n) offsets[idx + 1] = sm[t];
    if (t == 255) bsums[b] = sm[255];
}

__global__ __launch_bounds__(256) void scanB_kernel(int* __restrict__ bsums, int nb) {
    __shared__ int sm[256];
    int t = threadIdx.x;
    int v = (t < nb) ? bsums[t] : 0;
    sm[t] = v;
    __syncthreads();
    #pragma unroll
    for (int off = 1; off < 256; off <<= 1) {
        int u = (t >= off) ? sm[t - off] : 0;
        __syncthreads();
        sm[t] += u;
        __syncthreads();
    }
    if (t < nb) bsums[t] = sm[t] - v;
}

__global__ __launch_bounds__(256) void scanC_kernel(const int* __restrict__ counts,
                                                    const int* __restrict__ bsums,
                                                    int* __restrict__ offsets,
                                                    float* __restrict__ dinv,
                                                    int* __restrict__ cursor, int n) {
    int b = blockIdx.x;
    int idx = b * 256 + threadIdx.x;
    if (idx == 0) offsets[0] = 0;
    if (idx < n) {
        int incl = offsets[idx + 1] + bsums[b];
        offsets[idx + 1] = incl;
        cursor[idx] = incl - counts[idx];
        dinv[idx] = rsqrtf((float)(counts[idx] + 1));  // +1 self-loop
    }
}

__global__ void scatter_kernel(const int* __restrict__ ei, int E, const int* __restrict__ flags,
                               const float* __restrict__ dinv, int* __restrict__ cursor,
                               int* __restrict__ csr_src, float* __restrict__ csr_norm) {
    int e = blockIdx.x * blockDim.x + threadIdx.x;
    if (e < E) {
        int s = load_edge(ei, E, flags[0], 0, e);
        int d = load_edge(ei, E, flags[0], 1, e);
        int pos = atomicAdd(&cursor[d], 1);
        if (pos >= 0 && pos < E) {
            csr_src[pos] = s;
            csr_norm[pos] = dinv[s] * dinv[d];
        }
    }
}

// ---------------- weight prep: fp32 W[k][n] -> bf16 split-transposed Wt_hi/lo[n][k] ----------------

__global__ void convertT_w_kernel(const float* __restrict__ W,
                                  bf16_t* __restrict__ Wt_hi, bf16_t* __restrict__ Wt_lo) {
    int nn = blockIdx.x, k = threadIdx.x;
    float v = W[k * DIM + nn];
    bf16_t hi = (bf16_t)v;
    Wt_hi[nn * DIM + k] = hi;
    Wt_lo[nn * DIM + k] = (bf16_t)(v - (float)hi);
}

// ---------------- GEMM (fp32 A input, layer 1): P[M,256](bf16) = X @ W ----------------
// Block = 4 waves, 8 row-tiles. B slice [256n x 32k] hi+lo in LDS, rows padded to 40 shorts.

__global__ __launch_bounds__(256) void gemm_f32_kernel(const float* __restrict__ X,
                                                       const bf16_t* __restrict__ Wth,
                                                       const bf16_t* __restrict__ Wtl,
                                                       bf16_t* __restrict__ H, int M) {
    __shared__ bf16_t sBh[256 * 40];
    __shared__ bf16_t sBl[256 * 40];
    int tid  = threadIdx.x;
    int wave = tid >> 6, lane = tid & 63;
    int m = lane & 15, quad = lane >> 4;
    int t0 = blockIdx.x * 8 + wave * 2;

    f32x4 acc[2][16] = {};

    for (int k0 = 0; k0 < DIM; k0 += 32) {
        {
            const bf16x8* gh = (const bf16x8*)(Wth + (size_t)tid * DIM + k0);
            const bf16x8* gl = (const bf16x8*)(Wtl + (size_t)tid * DIM + k0);
            bf16x8* dh = (bf16x8*)(sBh + tid * 40);
            bf16x8* dl = (bf16x8*)(sBl + tid * 40);
            #pragma unroll
            for (int j = 0; j < 4; j++) { dh[j] = gh[j]; dl[j] = gl[j]; }
        }
        __syncthreads();

        bf16x8 ah[2], al[2];
        #pragma unroll
        for (int r = 0; r < 2; r++) {
            int row = (t0 + r) * 16 + m;
            row = min(row, M - 1);
            const f32x4* xp = (const f32x4*)(X + (size_t)row * DIM + k0 + quad * 8);
            f32x4 x0 = xp[0], x1 = xp[1];
            #pragma unroll
            for (int j = 0; j < 4; j++) {
                bf16_t h0 = (bf16_t)x0[j];
                ah[r][j] = h0; al[r][j] = (bf16_t)(x0[j] - (float)h0);
                bf16_t h1 = (bf16_t)x1[j];
                ah[r][j + 4] = h1; al[r][j + 4] = (bf16_t)(x1[j] - (float)h1);
            }
        }

        #pragma unroll
        for (int nt = 0; nt < 16; nt++) {
            const bf16x8 bh = *(const bf16x8*)(sBh + (nt * 16 + m) * 40 + quad * 8);
            const bf16x8 bl = *(const bf16x8*)(sBl + (nt * 16 + m) * 40 + quad * 8);
            #pragma unroll
            for (int r = 0; r < 2; r++) {
                acc[r][nt] = __builtin_amdgcn_mfma_f32_16x16x32_bf16(al[r], bh, acc[r][nt], 0, 0, 0);
                acc[r][nt] = __builtin_amdgcn_mfma_f32_16x16x32_bf16(ah[r], bl, acc[r][nt], 0, 0, 0);
                acc[r][nt] = __builtin_amdgcn_mfma_f32_16x16x32_bf16(ah[r], bh, acc[r][nt], 0, 0, 0);
            }
        }
        __syncthreads();
    }

    #pragma unroll
    for (int r = 0; r < 2; r++) {
        int rowb = (t0 + r) * 16 + quad * 4;
        #pragma unroll
        for (int nt = 0; nt < 16; nt++) {
            #pragma unroll
            for (int rr = 0; rr < 4; rr++) {
                int row = rowb + rr;
                if (row < M) H[(size_t)row * DIM + nt * 16 + m] = (bf16_t)acc[r][nt][rr];
            }
        }
    }
}

// ---------------- GEMM (bf16 A input, layer 2): P = X2 @ W, 2 MFMAs (A exact bf16) ----------------

__global__ __launch_bounds__(256) void gemm_bf16_kernel(const bf16_t* __restrict__ X,
                                                        const bf16_t* __restrict__ Wth,
                                                        const bf16_t* __restrict__ Wtl,
                                                        bf16_t* __restrict__ H, int M) {
    __shared__ bf16_t sBh[256 * 40];
    __shared__ bf16_t sBl[256 * 40];
    int tid  = threadIdx.x;
    int wave = tid >> 6, lane = tid & 63;
    int m = lane & 15, quad = lane >> 4;
    int t0 = blockIdx.x * 8 + wave * 2;

    f32x4 acc[2][16] = {};

    for (int k0 = 0; k0 < DIM; k0 += 32) {
        {
            const bf16x8* gh = (const bf16x8*)(Wth + (size_t)tid * DIM + k0);
            const bf16x8* gl = (const bf16x8*)(Wtl + (size_t)tid * DIM + k0);
            bf16x8* dh = (bf16x8*)(sBh + tid * 40);
            bf16x8* dl = (bf16x8*)(sBl + tid * 40);
            #pragma unroll
            for (int j = 0; j < 4; j++) { dh[j] = gh[j]; dl[j] = gl[j]; }
        }
        __syncthreads();

        bf16x8 a[2];
        #pragma unroll
        for (int r = 0; r < 2; r++) {
            int row = (t0 + r) * 16 + m;
            row = min(row, M - 1);
            a[r] = *(const bf16x8*)(X + (size_t)row * DIM + k0 + quad * 8);
        }

        #pragma unroll
        for (int nt = 0; nt < 16; nt++) {
            const bf16x8 bh = *(const bf16x8*)(sBh + (nt * 16 + m) * 40 + quad * 8);
            const bf16x8 bl = *(const bf16x8*)(sBl + (nt * 16 + m) * 40 + quad * 8);
            #pragma unroll
            for (int r = 0; r < 2; r++) {
                acc[r][nt] = __builtin_amdgcn_mfma_f32_16x16x32_bf16(a[r], bl, acc[r][nt], 0, 0, 0);
                acc[r][nt] = __builtin_amdgcn_mfma_f32_16x16x32_bf16(a[r], bh, acc[r][nt], 0, 0, 0);
            }
        }
        __syncthreads();
    }

    #pragma unroll
    for (int r = 0; r < 2; r++) {
        int rowb = (t0 + r) * 16 + quad * 4;
        #pragma unroll
        for (int nt = 0; nt < 16; nt++) {
            #pragma unroll
            for (int rr = 0; rr < 4; rr++) {
                int row = rowb + rr;
                if (row < M) H[(size_t)row * DIM + nt * 16 + m] = (bf16_t)acc[r][nt][rr];
            }
        }
    }
}

// ---------------- Aggregation: bf16 H gather, fp32 accumulate, bf16 or fp32 out ----------------
// 4 nodes/block (1/wave); lane covers 4 features (bf16x4 = 8B/row/lane, 512B/row/wave).

template <bool OUT_BF16>
__global__ __launch_bounds__(256) void aggregate_kernel(const bf16_t* __restrict__ H,
                                                        const int* __restrict__ offsets,
                                                        const int* __restrict__ csr_src,
                                                        const float* __restrict__ csr_norm,
                                                        const float* __restrict__ dinv,
                                                        const float* __restrict__ bias,
                                                        void* __restrict__ outv, int n) {
    int g = threadIdx.x >> 6;
    int l = threadIdx.x & 63;
    int i = blockIdx.x * 4 + g;
    if (i >= n) return;
    float dii = dinv[i];

    auto cvt = [](bf16x4 v) -> f32x4 {
        f32x4 r;
        #pragma unroll
        for (int j = 0; j < 4; j++) r[j] = (float)v[j];
        return r;
    };

    f32x4 acc = cvt(*(const bf16x4*)(H + (size_t)i * DIM + l * 4)) * (dii * dii);
    int e0 = offsets[i], e1 = offsets[i + 1];
    int e = e0;
    for (; e + 4 <= e1; e += 4) {
        int s0 = csr_src[e], s1 = csr_src[e + 1], s2 = csr_src[e + 2], s3 = csr_src[e + 3];
        float w0 = csr_norm[e], w1 = csr_norm[e + 1], w2 = csr_norm[e + 2], w3 = csr_norm[e + 3];
        bf16x4 h0 = *(const bf16x4*)(H + (size_t)s0 * DIM + l * 4);
        bf16x4 h1 = *(const bf16x4*)(H + (size_t)s1 * DIM + l * 4);
        bf16x4 h2 = *(const bf16x4*)(H + (size_t)s2 * DIM + l * 4);
        bf16x4 h3 = *(const bf16x4*)(H + (size_t)s3 * DIM + l * 4);
        acc += cvt(h0) * w0 + cvt(h1) * w1 + cvt(h2) * w2 + cvt(h3) * w3;
    }
    for (; e < e1; e++) {
        acc += cvt(*(const bf16x4*)(H + (size_t)csr_src[e] * DIM + l * 4)) * csr_norm[e];
    }
    acc += *(const f32x4*)(bias + l * 4);
    #pragma unroll
    for (int j = 0; j < 4; j++) acc[j] = fmaxf(acc[j], 0.0f);

    if (OUT_BF16) {
        bf16x4 o;
        #pragma unroll
        for (int j = 0; j < 4; j++) o[j] = (bf16_t)acc[j];
        *(bf16x4*)((bf16_t*)outv + (size_t)i * DIM + l * 4) = o;
    } else {
        *(f32x4*)((float*)outv + (size_t)i * DIM + l * 4) = acc;
    }
}

// ---------------- launch ----------------

extern "C" void kernel_launch(void* const* d_in, const int* in_sizes, int n_in,
                              void* d_out, int out_size, void* d_ws, size_t ws_size,
                              hipStream_t stream) {
    const float* x  = (const float*)d_in[0];
    const int*   ei = (const int*)d_in[1];
    const float* W1 = (const float*)d_in[2];
    const float* b1 = (const float*)d_in[3];
    const float* W2 = (const float*)d_in[4];
    const float* b2 = (const float*)d_in[5];
    float* out = (float*)d_out;

    const int n = NNODES;
    const int E = in_sizes[1] / 2;
    const int nb = (n + 255) / 256;

    char* ws = (char*)d_ws;
    size_t off = 0;
    auto alloc = [&](size_t bytes) -> char* {
        char* p = ws + off;
        off += (bytes + 255) & ~(size_t)255;
        return p;
    };
    int*    flags    = (int*)alloc(256);
    float*  dinv     = (float*)alloc((size_t)n * 4);
    int*    counts   = (int*)alloc((size_t)n * 4);
    int*    offsets  = (int*)alloc((size_t)(n + 1) * 4);
    int*    cursor   = (int*)alloc((size_t)n * 4);
    int*    bsums    = (int*)alloc((size_t)nb * 4);
    int*    csr_src  = (int*)alloc((size_t)E * 4);
    float*  csr_norm = (float*)alloc((size_t)E * 4);
    bf16_t* Wt1h     = (bf16_t*)alloc((size_t)DIM * DIM * 2);
    bf16_t* Wt1l     = (bf16_t*)alloc((size_t)DIM * DIM * 2);
    bf16_t* Wt2h     = (bf16_t*)alloc((size_t)DIM * DIM * 2);
    bf16_t* Wt2l     = (bf16_t*)alloc((size_t)DIM * DIM * 2);
    bf16_t* P        = (bf16_t*)alloc((size_t)n * DIM * 2);   // GEMM output (bf16)
    bf16_t* X2       = (bf16_t*)alloc((size_t)n * DIM * 2);   // inter-layer activation (bf16)

    detect_kernel<<<1, 256, 0, stream>>>(ei, flags);
    zero_counts_kernel<<<nb, 256, 0, stream>>>(counts, n);
    hist_kernel<<<(E + 255) / 256, 256, 0, stream>>>(ei, E, flags, counts);
    scanA_kernel<<<nb, 256, 0, stream>>>(counts, offsets, bsums, n);
    scanB_kernel<<<1, 256, 0, stream>>>(bsums, nb);
    scanC_kernel<<<nb, 256, 0, stream>>>(counts, bsums, offsets, dinv, cursor, n);
    scatter_kernel<<<(E + 255) / 256, 256, 0, stream>>>(ei, E, flags, dinv, cursor,
                                                        csr_src, csr_norm);

    convertT_w_kernel<<<DIM, DIM, 0, stream>>>(W1, Wt1h, Wt1l);
    convertT_w_kernel<<<DIM, DIM, 0, stream>>>(W2, Wt2h, Wt2l);

    int tiles = (n + 15) / 16;                 // 3125
    int gemm_blocks = (tiles + 7) / 8;         // 391
    int agg_blocks = n / 4;                    // 12500

    gemm_f32_kernel<<<gemm_blocks, 256, 0, stream>>>(x, Wt1h, Wt1l, P, n);
    aggregate_kernel<true><<<agg_blocks, 256, 0, stream>>>(P, offsets, csr_src, csr_norm,
                                                           dinv, b1, X2, n);
    gemm_bf16_kernel<<<gemm_blocks, 256, 0, stream>>>(X2, Wt2h, Wt2l, P, n);
    aggregate_kernel<false><<<agg_blocks, 256, 0, stream>>>(P, offsets, csr_src, csr_norm,
                                                            dinv, b2, out, n);
}

// Round 7
// 270.947 us; speedup vs baseline: 2.5353x; 1.2409x over previous
//
#include <hip/hip_runtime.h>
#include <stdint.h>

typedef __bf16 bf16_t;
typedef bf16_t bf16x4 __attribute__((ext_vector_type(4)));
typedef bf16_t bf16x8 __attribute__((ext_vector_type(8)));
typedef float f32x4 __attribute__((ext_vector_type(4)));

#define DIM 256
#define NNODES 50000

// ---------------- edge dtype detection (int64 vs int32) ----------------
__global__ void detect_kernel(const int* __restrict__ ei, int* __restrict__ flags) {
    __shared__ int s_zero;
    if (threadIdx.x == 0) s_zero = 0;
    __syncthreads();
    int z = (ei[2 * threadIdx.x + 1] == 0) ? 1 : 0;   // odd words: int64 high halves == 0
    atomicAdd(&s_zero, z);
    __syncthreads();
    if (threadIdx.x == 0) flags[0] = (s_zero > 128) ? 1 : 0;
}

__device__ __forceinline__ int load_edge(const int* __restrict__ ei, int E, int f64,
                                         int which /*0=src,1=dst*/, int e) {
    int v = f64 ? ei[(size_t)which * 2 * E + 2 * (size_t)e]   // int64 low word (LE)
                : ei[(size_t)which * E + (size_t)e];
    return min(max(v, 0), NNODES - 1);
}

// ---------------- CSR build ----------------

__global__ void zero_counts_kernel(int* __restrict__ counts, int n) {
    int i = blockIdx.x * blockDim.x + threadIdx.x;
    if (i < n) counts[i] = 0;
}

__global__ void hist_kernel(const int* __restrict__ ei, int E, const int* __restrict__ flags,
                            int* __restrict__ counts) {
    int e = blockIdx.x * blockDim.x + threadIdx.x;
    if (e < E) atomicAdd(&counts[load_edge(ei, E, flags[0], 1, e)], 1);
}

__global__ __launch_bounds__(256) void scanA_kernel(const int* __restrict__ counts,
                                                    int* __restrict__ offsets,
                                                    int* __restrict__ bsums, int n) {
    __shared__ int sm[256];
    int b = blockIdx.x, t = threadIdx.x;
    int idx = b * 256 + t;
    int v = (idx < n) ? counts[idx] : 0;
    sm[t] = v;
    __syncthreads();
    #pragma unroll
    for (int off = 1; off < 256; off <<= 1) {
        int u = (t >= off) ? sm[t - off] : 0;
        __syncthreads();
        sm[t] += u;
        __syncthreads();
    }
    if (idx < n) offsets[idx + 1] = sm[t];
    if (t == 255) bsums[b] = sm[255];
}

__global__ __launch_bounds__(256) void scanB_kernel(int* __restrict__ bsums, int nb) {
    __shared__ int sm[256];
    int t = threadIdx.x;
    int v = (t < nb) ? bsums[t] : 0;
    sm[t] = v;
    __syncthreads();
    #pragma unroll
    for (int off = 1; off < 256; off <<= 1) {
        int u = (t >= off) ? sm[t - off] : 0;
        __syncthreads();
        sm[t] += u;
        __syncthreads();
    }
    if (t < nb) bsums[t] = sm[t] - v;
}

__global__ __launch_bounds__(256) void scanC_kernel(const int* __restrict__ counts,
                                                    const int* __restrict__ bsums,
                                                    int* __restrict__ offsets,
                                                    float* __restrict__ dinv,
                                                    int* __restrict__ cursor, int n) {
    int b = blockIdx.x;
    int idx = b * 256 + threadIdx.x;
    if (idx == 0) offsets[0] = 0;
    if (idx < n) {
        int incl = offsets[idx + 1] + bsums[b];
        offsets[idx + 1] = incl;
        cursor[idx] = incl - counts[idx];
        dinv[idx] = rsqrtf((float)(counts[idx] + 1));  // +1 self-loop
    }
}

__global__ void scatter_kernel(const int* __restrict__ ei, int E, const int* __restrict__ flags,
                               const float* __restrict__ dinv, int* __restrict__ cursor,
                               int* __restrict__ csr_src, float* __restrict__ csr_norm) {
    int e = blockIdx.x * blockDim.x + threadIdx.x;
    if (e < E) {
        int s = load_edge(ei, E, flags[0], 0, e);
        int d = load_edge(ei, E, flags[0], 1, e);
        int pos = atomicAdd(&cursor[d], 1);
        if (pos >= 0 && pos < E) {
            csr_src[pos] = s;
            csr_norm[pos] = dinv[s] * dinv[d];
        }
    }
}

// ---------------- weight prep: fp32 W[k][n] -> fragment-order bf16 Wf ----------------
// Wf layout: slice s = k>>5 (8 slices); frag f = nt*64 + quad*16 + m where
// n = nt*16+m, k = s*32 + quad*8 + j. Flat short index: s*8192 + f*8 + j.
// This makes LDS staging a sequential copy and B-frag reads conflict-free.

__global__ void convert_w_kernel(const float* __restrict__ W1, const float* __restrict__ W2,
                                 bf16_t* __restrict__ Wf1, bf16_t* __restrict__ Wf2) {
    const float* W = blockIdx.y ? W2 : W1;
    bf16_t* Wf = blockIdx.y ? Wf2 : Wf1;
    int k = blockIdx.x, n = threadIdx.x;      // read W[k][n] coalesced per block
    int s = k >> 5, quad = (k >> 3) & 3, j = k & 7;
    int nt = n >> 4, m = n & 15;
    Wf[s * 8192 + (nt * 64 + quad * 16 + m) * 8 + j] = (bf16_t)W[k * DIM + n];
}

// ---------------- GEMM: H[M,256](bf16) = X[M,256] @ W ----------------
// 1 row-tile (16 rows) per wave, 4 waves/block -> 64 rows/block, grid = 782.
// W staged per 32-k slice in fragment order: 16 KB LDS, zero bank conflicts.
// acc[16] = 64 VGPRs; __launch_bounds__(256,4) targets 4 waves/SIMD.

template <bool F32A>
__global__ __launch_bounds__(256, 4) void gemm_kernel(const void* __restrict__ Xv,
                                                      const bf16_t* __restrict__ Wf,
                                                      bf16_t* __restrict__ H, int tiles) {
    __shared__ bf16_t sB[8192];               // 256n x 32k slice, fragment order
    int tid = threadIdx.x;
    int wave = tid >> 6, lane = tid & 63;
    int m = lane & 15, quad = lane >> 4;
    int tile = blockIdx.x * 4 + wave;
    bool active = tile < tiles;
    int arow = (min(tile, tiles - 1)) * 16 + m;   // clamped; store predicated below

    f32x4 acc[16] = {};

    for (int s = 0; s < 8; s++) {
        __syncthreads();                      // protect previous slice's reads
        {
            const bf16x8* g = (const bf16x8*)Wf + s * 1024;
            bf16x8* d = (bf16x8*)sB;
            #pragma unroll
            for (int it = 0; it < 4; it++) d[tid + it * 256] = g[tid + it * 256];
        }
        __syncthreads();

        // A fragment: A[m=lane&15][k = s*32 + quad*8 + j]
        bf16x8 a;
        if (F32A) {
            const f32x4* xp = (const f32x4*)((const float*)Xv + (size_t)arow * DIM + s * 32 + quad * 8);
            f32x4 x0 = xp[0], x1 = xp[1];
            #pragma unroll
            for (int j = 0; j < 4; j++) { a[j] = (bf16_t)x0[j]; a[j + 4] = (bf16_t)x1[j]; }
        } else {
            a = *(const bf16x8*)((const bf16_t*)Xv + (size_t)arow * DIM + s * 32 + quad * 8);
        }

        #pragma unroll
        for (int nt = 0; nt < 16; nt++) {
            bf16x8 b = *(const bf16x8*)(sB + nt * 512 + lane * 8);  // sequential: no conflicts
            acc[nt] = __builtin_amdgcn_mfma_f32_16x16x32_bf16(a, b, acc[nt], 0, 0, 0);
        }
    }

    if (active) {
        int rowb = tile * 16 + quad * 4;
        #pragma unroll
        for (int nt = 0; nt < 16; nt++) {
            #pragma unroll
            for (int r = 0; r < 4; r++) {
                H[(size_t)(rowb + r) * DIM + nt * 16 + m] = (bf16_t)acc[nt][r];
            }
        }
    }
}

// ---------------- Aggregation: bf16 H gather, fp32 accumulate ----------------

template <bool OUT_BF16>
__global__ __launch_bounds__(256) void aggregate_kernel(const bf16_t* __restrict__ H,
                                                        const int* __restrict__ offsets,
                                                        const int* __restrict__ csr_src,
                                                        const float* __restrict__ csr_norm,
                                                        const float* __restrict__ dinv,
                                                        const float* __restrict__ bias,
                                                        void* __restrict__ outv, int n) {
    int g = threadIdx.x >> 6;
    int l = threadIdx.x & 63;
    int i = blockIdx.x * 4 + g;
    if (i >= n) return;
    float dii = dinv[i];

    auto cvt = [](bf16x4 v) -> f32x4 {
        f32x4 r;
        #pragma unroll
        for (int j = 0; j < 4; j++) r[j] = (float)v[j];
        return r;
    };

    f32x4 acc = cvt(*(const bf16x4*)(H + (size_t)i * DIM + l * 4)) * (dii * dii);
    int e0 = offsets[i], e1 = offsets[i + 1];
    int e = e0;
    for (; e + 4 <= e1; e += 4) {
        int s0 = csr_src[e], s1 = csr_src[e + 1], s2 = csr_src[e + 2], s3 = csr_src[e + 3];
        float w0 = csr_norm[e], w1 = csr_norm[e + 1], w2 = csr_norm[e + 2], w3 = csr_norm[e + 3];
        bf16x4 h0 = *(const bf16x4*)(H + (size_t)s0 * DIM + l * 4);
        bf16x4 h1 = *(const bf16x4*)(H + (size_t)s1 * DIM + l * 4);
        bf16x4 h2 = *(const bf16x4*)(H + (size_t)s2 * DIM + l * 4);
        bf16x4 h3 = *(const bf16x4*)(H + (size_t)s3 * DIM + l * 4);
        acc += cvt(h0) * w0 + cvt(h1) * w1 + cvt(h2) * w2 + cvt(h3) * w3;
    }
    for (; e < e1; e++) {
        acc += cvt(*(const bf16x4*)(H + (size_t)csr_src[e] * DIM + l * 4)) * csr_norm[e];
    }
    acc += *(const f32x4*)(bias + l * 4);
    #pragma unroll
    for (int j = 0; j < 4; j++) acc[j] = fmaxf(acc[j], 0.0f);

    if (OUT_BF16) {
        bf16x4 o;
        #pragma unroll
        for (int j = 0; j < 4; j++) o[j] = (bf16_t)acc[j];
        *(bf16x4*)((bf16_t*)outv + (size_t)i * DIM + l * 4) = o;
    } else {
        *(f32x4*)((float*)outv + (size_t)i * DIM + l * 4) = acc;
    }
}

// ---------------- launch ----------------

extern "C" void kernel_launch(void* const* d_in, const int* in_sizes, int n_in,
                              void* d_out, int out_size, void* d_ws, size_t ws_size,
                              hipStream_t stream) {
    const float* x  = (const float*)d_in[0];
    const int*   ei = (const int*)d_in[1];
    const float* W1 = (const float*)d_in[2];
    const float* b1 = (const float*)d_in[3];
    const float* W2 = (const float*)d_in[4];
    const float* b2 = (const float*)d_in[5];
    float* out = (float*)d_out;

    const int n = NNODES;
    const int E = in_sizes[1] / 2;
    const int nb = (n + 255) / 256;

    char* ws = (char*)d_ws;
    size_t off = 0;
    auto alloc = [&](size_t bytes) -> char* {
        char* p = ws + off;
        off += (bytes + 255) & ~(size_t)255;
        return p;
    };
    int*    flags    = (int*)alloc(256);
    float*  dinv     = (float*)alloc((size_t)n * 4);
    int*    counts   = (int*)alloc((size_t)n * 4);
    int*    offsets  = (int*)alloc((size_t)(n + 1) * 4);
    int*    cursor   = (int*)alloc((size_t)n * 4);
    int*    bsums    = (int*)alloc((size_t)nb * 4);
    int*    csr_src  = (int*)alloc((size_t)E * 4);
    float*  csr_norm = (float*)alloc((size_t)E * 4);
    bf16_t* Wf1      = (bf16_t*)alloc((size_t)DIM * DIM * 2);
    bf16_t* Wf2      = (bf16_t*)alloc((size_t)DIM * DIM * 2);
    bf16_t* P        = (bf16_t*)alloc((size_t)n * DIM * 2);   // GEMM output (bf16)
    bf16_t* X2       = (bf16_t*)alloc((size_t)n * DIM * 2);   // inter-layer activation (bf16)

    detect_kernel<<<1, 256, 0, stream>>>(ei, flags);
    zero_counts_kernel<<<nb, 256, 0, stream>>>(counts, n);
    hist_kernel<<<(E + 255) / 256, 256, 0, stream>>>(ei, E, flags, counts);
    scanA_kernel<<<nb, 256, 0, stream>>>(counts, offsets, bsums, n);
    scanB_kernel<<<1, 256, 0, stream>>>(bsums, nb);
    scanC_kernel<<<nb, 256, 0, stream>>>(counts, bsums, offsets, dinv, cursor, n);
    scatter_kernel<<<(E + 255) / 256, 256, 0, stream>>>(ei, E, flags, dinv, cursor,
                                                        csr_src, csr_norm);

    convert_w_kernel<<<dim3(DIM, 2), DIM, 0, stream>>>(W1, W2, Wf1, Wf2);

    int tiles = (n + 15) / 16;                 // 3125 (exact: 50000 = 16*3125)
    int gemm_blocks = (tiles + 3) / 4;         // 782
    int agg_blocks = n / 4;                    // 12500

    gemm_kernel<true><<<gemm_blocks, 256, 0, stream>>>(x, Wf1, P, tiles);
    aggregate_kernel<true><<<agg_blocks, 256, 0, stream>>>(P, offsets, csr_src, csr_norm,
                                                           dinv, b1, X2, n);
    gemm_kernel<false><<<gemm_blocks, 256, 0, stream>>>(X2, Wf2, P, tiles);
    aggregate_kernel<false><<<agg_blocks, 256, 0, stream>>>(P, offsets, csr_src, csr_norm,
                                                            dinv, b2, out, n);
}